// Round 6
// baseline (298.802 us; speedup 1.0000x reference)
//
#include <hip/hip_runtime.h>
#include <hip/hip_bf16.h>
#include <cstddef>

// Problem constants
#define BB 8
#define DIM 256
#define HH 48
#define WW 48
#define HW 2304        // 48*48
#define HEADS 8
#define DH 32
#define BH 64          // B*HEADS
#define HK 24
#define WK 24
#define NN 576         // HK*WK
#define SCALE 0.17677669529663687f
#define EPSF 1e-5f

typedef __attribute__((ext_vector_type(8))) short short8;
typedef __attribute__((ext_vector_type(4))) float f32x4;

static __device__ inline short f2bf_s(float f) {
  __hip_bfloat16 h = __float2bfloat16(f);
  return *reinterpret_cast<short*>(&h);
}

template <typename T> __device__ inline T cvt_out(float v);
template <> __device__ inline float cvt_out<float>(float v) { return v; }
template <> __device__ inline __hip_bfloat16 cvt_out<__hip_bfloat16>(float v) {
  return __float2bfloat16(v);
}

// pack two floats into bf16 pair (round-half-up): lo short = a, hi short = b
static __device__ inline unsigned pkrnd(float a, float b) {
  unsigned ua = __builtin_bit_cast(unsigned, a) + 0x8000u;
  unsigned ub = __builtin_bit_cast(unsigned, b) + 0x8000u;
  return __builtin_amdgcn_perm(ub, ua, 0x07060302);
}

// in-register split of 8 fp32 into bf16 hi/lo fragments (truncation split)
static __device__ inline void split8(const float* xf, short8& bh, short8& bl) {
  union { unsigned u[4]; short8 v; } H, L;
#pragma unroll
  for (int p = 0; p < 4; p++) {
    float x0 = xf[2 * p], x1 = xf[2 * p + 1];
    unsigned u0 = __builtin_bit_cast(unsigned, x0) & 0xffff0000u;
    unsigned u1 = __builtin_bit_cast(unsigned, x1) & 0xffff0000u;
    float l0 = x0 - __builtin_bit_cast(float, u0);
    float l1 = x1 - __builtin_bit_cast(float, u1);
    H.u[p] = __builtin_amdgcn_perm(u1, u0, 0x07060302);
    L.u[p] = __builtin_amdgcn_perm(__builtin_bit_cast(unsigned, l1),
                                   __builtin_bit_cast(unsigned, l0), 0x07060302);
  }
  bh = H.v;
  bl = L.v;
}

// ---------------------------------------------------------------------------
// Split 4 weight matrices (each 65536 fp32) into bf16 hi/lo planes.
// ---------------------------------------------------------------------------
__global__ __launch_bounds__(256) void split4(
    const float* __restrict__ w0, const float* __restrict__ w1,
    const float* __restrict__ w2, const float* __restrict__ w3,
    short* __restrict__ h0, short* __restrict__ l0,
    short* __restrict__ h1, short* __restrict__ l1,
    short* __restrict__ h2, short* __restrict__ l2,
    short* __restrict__ h3, short* __restrict__ l3) {
  const float* srcs[4] = {w0, w1, w2, w3};
  short* his[4] = {h0, h1, h2, h3};
  short* los[4] = {l0, l1, l2, l3};
  int sel = blockIdx.x >> 8;
  int i = (blockIdx.x & 255) * 256 + threadIdx.x;
  float v = srcs[sel][i];
  unsigned u = __builtin_bit_cast(unsigned, v) & 0xffff0000u;
  float rem = v - __builtin_bit_cast(float, u);
  his[sel][i] = (short)(u >> 16);
  los[sel][i] = (short)(__builtin_bit_cast(unsigned, rem) >> 16);
}

// ---------------------------------------------------------------------------
// q GEMM (4-wave blocks): wave w owns o-tile 64 (o = w*64..), block owns
// m-tile 64 → X tile loaded once per block (4x L1-shared across waves).
// Grid (HW/64, BB), 256 threads.
// ---------------------------------------------------------------------------
__global__ __launch_bounds__(256) void gemm_q_mfma(const short* __restrict__ Wh,
                                                   const short* __restrict__ Wl,
                                                   const float* __restrict__ bias,
                                                   const float* __restrict__ X,
                                                   float* __restrict__ Y) {
  const int tid = threadIdx.x;
  const int wave = tid >> 6;
  const int lane = tid & 63;
  const int quad = lane >> 4, l15 = lane & 15;
  const int b = blockIdx.y;
  const int oBase = wave * 64;
  const int mBase = blockIdx.x * 64;
  const float* Xq = X + ((size_t)b * 256 + quad * 8) * HW;

  f32x4 acc[4][4] = {};
  for (int kc = 0; kc < 256; kc += 32) {
    short8 ah[4], al[4];
#pragma unroll
    for (int os = 0; os < 4; os++) {
      ah[os] = *(const short8*)(Wh + (size_t)(oBase + os * 16 + l15) * 256 + kc + quad * 8);
      al[os] = *(const short8*)(Wl + (size_t)(oBase + os * 16 + l15) * 256 + kc + quad * 8);
    }
#pragma unroll
    for (int mt = 0; mt < 4; mt++) {
      float xf[8];
      const float* xp = Xq + (size_t)kc * HW + mBase + mt * 16 + l15;
#pragma unroll
      for (int j = 0; j < 8; j++) xf[j] = xp[(size_t)j * HW];
      short8 bh, bl;
      split8(xf, bh, bl);
#pragma unroll
      for (int os = 0; os < 4; os++) {
        acc[os][mt] = __builtin_amdgcn_mfma_f32_16x16x32_bf16(ah[os], bh, acc[os][mt], 0, 0, 0);
        acc[os][mt] = __builtin_amdgcn_mfma_f32_16x16x32_bf16(al[os], bh, acc[os][mt], 0, 0, 0);
        acc[os][mt] = __builtin_amdgcn_mfma_f32_16x16x32_bf16(ah[os], bl, acc[os][mt], 0, 0, 0);
      }
    }
  }

#pragma unroll
  for (int os = 0; os < 4; os++)
#pragma unroll
    for (int r = 0; r < 4; r++) {
      int o = oBase + os * 16 + quad * 4 + r;
      float bs = bias[o];
      float* yp = Y + ((size_t)b * 256 + o) * HW + mBase + l15;
#pragma unroll
      for (int mt = 0; mt < 4; mt++) yp[mt * 16] = acc[os][mt][r] + bs;
    }
}

// ---------------------------------------------------------------------------
// MFMA GEMM, A = W (o rows, split bf16), B = X fp32 c-major split in-register.
// 1 wave per block: o-tile 32, m-tile 64. Grid (M/64, 256/32, B). Used for v.
// ---------------------------------------------------------------------------
template <typename OT>
__global__ __launch_bounds__(64) void gemm_axf_mfma(const short* __restrict__ Wh,
                                                    const short* __restrict__ Wl,
                                                    const float* __restrict__ bias,
                                                    const float* __restrict__ X,
                                                    OT* __restrict__ Y, int M) {
  const int lane = threadIdx.x;
  const int quad = lane >> 4, l15 = lane & 15;
  const int b = blockIdx.z;
  const int oBase = blockIdx.y * 32;
  const int mBase = blockIdx.x * 64;
  const float* Xq = X + ((size_t)b * 256 + quad * 8) * M;

  f32x4 acc[2][4] = {};
  for (int kc = 0; kc < 256; kc += 32) {
    short8 ah0 = *(const short8*)(Wh + (size_t)(oBase + l15) * 256 + kc + quad * 8);
    short8 al0 = *(const short8*)(Wl + (size_t)(oBase + l15) * 256 + kc + quad * 8);
    short8 ah1 = *(const short8*)(Wh + (size_t)(oBase + 16 + l15) * 256 + kc + quad * 8);
    short8 al1 = *(const short8*)(Wl + (size_t)(oBase + 16 + l15) * 256 + kc + quad * 8);
#pragma unroll
    for (int mt = 0; mt < 4; mt++) {
      float xf[8];
      const float* xp = Xq + (size_t)kc * M + mBase + mt * 16 + l15;
#pragma unroll
      for (int j = 0; j < 8; j++) xf[j] = xp[(size_t)j * M];
      short8 bh, bl;
      split8(xf, bh, bl);
      acc[0][mt] = __builtin_amdgcn_mfma_f32_16x16x32_bf16(ah0, bh, acc[0][mt], 0, 0, 0);
      acc[0][mt] = __builtin_amdgcn_mfma_f32_16x16x32_bf16(al0, bh, acc[0][mt], 0, 0, 0);
      acc[0][mt] = __builtin_amdgcn_mfma_f32_16x16x32_bf16(ah0, bl, acc[0][mt], 0, 0, 0);
      acc[1][mt] = __builtin_amdgcn_mfma_f32_16x16x32_bf16(ah1, bh, acc[1][mt], 0, 0, 0);
      acc[1][mt] = __builtin_amdgcn_mfma_f32_16x16x32_bf16(al1, bh, acc[1][mt], 0, 0, 0);
      acc[1][mt] = __builtin_amdgcn_mfma_f32_16x16x32_bf16(ah1, bl, acc[1][mt], 0, 0, 0);
    }
  }

#pragma unroll
  for (int os = 0; os < 2; os++)
#pragma unroll
    for (int r = 0; r < 4; r++) {
      int o = oBase + os * 16 + quad * 4 + r;
      float bs = bias[o];
      OT* yp = Y + ((size_t)b * 256 + o) * M + mBase + l15;
#pragma unroll
      for (int mt = 0; mt < 4; mt++) yp[mt * 16] = cvt_out<OT>(acc[os][mt][r] + bs);
    }
}

// ---------------------------------------------------------------------------
// K GEMM producing K^T directly: Kb[b,n,o] = sum_c kvs[b,c,n]*Wk[o,c] + bk[o].
// ---------------------------------------------------------------------------
__global__ __launch_bounds__(64) void k_gemm_mfma(const short* __restrict__ Wh,
                                                  const short* __restrict__ Wl,
                                                  const float* __restrict__ bias,
                                                  const float* __restrict__ X,
                                                  short* __restrict__ Y) {
  const int lane = threadIdx.x;
  const int quad = lane >> 4, l15 = lane & 15;
  const int b = blockIdx.z;
  const int nBase = blockIdx.x * 32;
  const int oBase = blockIdx.y * 64;
  const float* Xq = X + ((size_t)b * 256 + quad * 8) * NN;

  f32x4 acc[2][4] = {};
  for (int kc = 0; kc < 256; kc += 32) {
    short8 ah[2], al[2];
#pragma unroll
    for (int ns = 0; ns < 2; ns++) {
      float xf[8];
      const float* xp = Xq + (size_t)kc * NN + nBase + ns * 16 + l15;
#pragma unroll
      for (int j = 0; j < 8; j++) xf[j] = xp[(size_t)j * NN];
      split8(xf, ah[ns], al[ns]);
    }
#pragma unroll
    for (int ot = 0; ot < 4; ot++) {
      short8 bh = *(const short8*)(Wh + (size_t)(oBase + ot * 16 + l15) * 256 + kc + quad * 8);
      short8 bl = *(const short8*)(Wl + (size_t)(oBase + ot * 16 + l15) * 256 + kc + quad * 8);
#pragma unroll
      for (int ns = 0; ns < 2; ns++) {
        acc[ns][ot] = __builtin_amdgcn_mfma_f32_16x16x32_bf16(ah[ns], bh, acc[ns][ot], 0, 0, 0);
        acc[ns][ot] = __builtin_amdgcn_mfma_f32_16x16x32_bf16(al[ns], bh, acc[ns][ot], 0, 0, 0);
        acc[ns][ot] = __builtin_amdgcn_mfma_f32_16x16x32_bf16(ah[ns], bl, acc[ns][ot], 0, 0, 0);
      }
    }
  }

  float bs[4];
#pragma unroll
  for (int ot = 0; ot < 4; ot++) bs[ot] = bias[oBase + ot * 16 + l15];
#pragma unroll
  for (int ns = 0; ns < 2; ns++)
#pragma unroll
    for (int r = 0; r < 4; r++) {
      int n = nBase + ns * 16 + quad * 4 + r;
      short* yp = Y + ((size_t)b * NN + n) * 256 + oBase + l15;
#pragma unroll
      for (int ot = 0; ot < 4; ot++) yp[ot * 16] = f2bf_s(acc[ns][ot][r] + bs[ot]);
    }
}

// ---------------------------------------------------------------------------
// dw conv + LN + GELU + offsets + bilinear sample, channel-split version:
// lane = cg*16 + nl; cg owns 8 channels, nl owns one n. LN/offset reductions
// via shfl_xor(16/32). Grid: BH * NN/16 = 2304 blocks x 64 threads.
// ---------------------------------------------------------------------------
__global__ __launch_bounds__(64) void dw_sample_kernel(
    const float* __restrict__ q, const float* __restrict__ kv,
    const float* __restrict__ w_dw, const float* __restrict__ b_dw,
    const float* __restrict__ ln_w, const float* __restrict__ ln_b,
    const float* __restrict__ w_off, float* __restrict__ kvs) {
  __shared__ float s_wdw[DH * 25];
  __shared__ float s_bdw[DH], s_lnw[DH], s_lnb[DH], s_woff[2 * DH];
  const int tid = threadIdx.x;
  for (int i = tid; i < DH * 25; i += 64) s_wdw[i] = w_dw[i];
  if (tid < DH) { s_bdw[tid] = b_dw[tid]; s_lnw[tid] = ln_w[tid]; s_lnb[tid] = ln_b[tid]; }
  if (tid < 2 * DH) s_woff[tid] = w_off[tid];
  __syncthreads();

  const int nl = tid & 15, cg = tid >> 4;
  const int c0 = cg * 8;
  const int bh = blockIdx.x / (NN / 16);
  const int ntile = blockIdx.x - bh * (NN / 16);
  const int n = ntile * 16 + nl;
  const int yk = n / WK, xk = n - yk * WK;

  const float* qb = q + (size_t)bh * DH * HW;
  float t[8];
#pragma unroll
  for (int j = 0; j < 8; j++) t[j] = s_bdw[c0 + j];

  const int y0r = yk * 2 - 2, x0r = xk * 2 - 2;
  for (int dy = 0; dy < 5; dy++) {
    int y = y0r + dy;
    if (y < 0 || y >= HH) continue;
    for (int dx = 0; dx < 5; dx++) {
      int x = x0r + dx;
      if (x < 0 || x >= WW) continue;
      int off = y * WW + x;
      int widx = dy * 5 + dx;
#pragma unroll
      for (int j = 0; j < 8; j++)
        t[j] += s_wdw[(c0 + j) * 25 + widx] * qb[(size_t)(c0 + j) * HW + off];
    }
  }

  // LN over 32 channels: partial sums + cross-cg shuffles
  float mu = 0.f;
#pragma unroll
  for (int j = 0; j < 8; j++) mu += t[j];
  mu += __shfl_xor(mu, 16);
  mu += __shfl_xor(mu, 32);
  mu *= (1.0f / DH);
  float var = 0.f;
#pragma unroll
  for (int j = 0; j < 8; j++) { float d = t[j] - mu; var += d * d; }
  var += __shfl_xor(var, 16);
  var += __shfl_xor(var, 32);
  var *= (1.0f / DH);
  float rstd = rsqrtf(var + EPSF);

  float o0 = 0.f, o1 = 0.f;
#pragma unroll
  for (int j = 0; j < 8; j++) {
    float xn = (t[j] - mu) * rstd * s_lnw[c0 + j] + s_lnb[c0 + j];
    float g = 0.5f * xn * (1.0f + erff(xn * 0.70710678118654752f));
    o0 += s_woff[c0 + j] * g;
    o1 += s_woff[DH + c0 + j] * g;
  }
  o0 += __shfl_xor(o0, 16);
  o0 += __shfl_xor(o0, 32);
  o1 += __shfl_xor(o1, 16);
  o1 += __shfl_xor(o1, 32);

  const float ref_y = (0.5f + (float)yk) / 23.0f * 2.0f - 1.0f;
  const float ref_x = (0.5f + (float)xk) / 23.0f * 2.0f - 1.0f;
  float py = fminf(fmaxf(o0 + ref_y, -1.0f), 1.0f);
  float px = fminf(fmaxf(o1 + ref_x, -1.0f), 1.0f);

  float gx = (px + 1.0f) * 0.5f * 47.0f;
  float gy = (py + 1.0f) * 0.5f * 47.0f;
  float x0f = floorf(gx), y0f = floorf(gy);
  float wx = gx - x0f, wy = gy - y0f;
  int x0 = (int)x0f, y0 = (int)y0f;
  int x0i = min(max(x0, 0), WW - 1);
  int x1i = min(max(x0 + 1, 0), WW - 1);
  int y0i = min(max(y0, 0), HH - 1);
  int y1i = min(max(y0 + 1, 0), HH - 1);
  float w00 = (1.f - wx) * (1.f - wy);
  float w01 = wx * (1.f - wy);
  float w10 = (1.f - wx) * wy;
  float w11 = wx * wy;
  int i00 = y0i * WW + x0i, i01 = y0i * WW + x1i;
  int i10 = y1i * WW + x0i, i11 = y1i * WW + x1i;

  const float* kvb = kv + ((size_t)bh * DH + c0) * HW;
#pragma unroll
  for (int j = 0; j < 8; j++) {
    const float* p = kvb + (size_t)j * HW;
    float val = w00 * p[i00] + w01 * p[i01] + w10 * p[i10] + w11 * p[i11];
    kvs[((size_t)bh * DH + c0 + j) * NN + n] = val;
  }
}

// ---------------------------------------------------------------------------
// MFMA attention v5: mt=1 (16 m rows/wave), fixed conflict-free swizzle
// (XOR term (l15>>1)&3), double-buffered wave-private LDS.
// Grid (HW/64 = 36, 64 bh), 256 threads (4 waves).
// ---------------------------------------------------------------------------
__global__ __launch_bounds__(256) void attn_mfma(const float* __restrict__ q,
                                                 const short* __restrict__ Kb,
                                                 const short* __restrict__ Vb,
                                                 short* __restrict__ O) {
  __shared__ int smem[2][4][256];  // [dbuf][wave][16 rows x 16 dwords]
  const int tid = threadIdx.x;
  const int wave = tid >> 6;
  const int lane = tid & 63;
  const int quad = lane >> 4;
  const int l15 = lane & 15;
  const int bh = blockIdx.y;
  const int b = bh >> 3, head = bh & 7;
  const int mBase = blockIdx.x * 64 + wave * 16;

  // Q B-frag (SCALE folded): B[k=c=quad*8+j][col=m=l15]
  short8 bq;
  {
    const float* qp = q + ((size_t)bh * DH + quad * 8) * HW + mBase + l15;
#pragma unroll
    for (int j = 0; j < 8; j++) bq[j] = f2bf_s(qp[(size_t)j * HW] * SCALE);
  }

  const short* kbase = Kb + (size_t)b * NN * 256 + head * DH + quad * 8;
  const short* vb0 = Vb + ((size_t)b * 256 + head * DH + l15) * NN + quad * 8;
  const short* vb1 = vb0 + (size_t)16 * NN;

  f32x4 oacc0 = {}, oacc1 = {};
  float dsum = 0.f;

  // swizzle: phys_chunk = chunk_log ^ ((l15>>1)&3)  (reads conflict-free,
  // b64 writes at free 2-way; rows stride 16 dwords)
  const int g = (l15 >> 1) & 3;
  const int row16 = l15 * 16;
  const int wr0 = row16 + ((((quad >> 1)) ^ g) << 2) + ((quad & 1) << 1);
  const int wr1 = row16 + (((2 + (quad >> 1)) ^ g) << 2) + ((quad & 1) << 1);
  const int rd = row16 + ((quad ^ g) << 2);

  short8 ka0 = *(const short8*)(kbase + (size_t)l15 * 256);
  short8 ka1 = *(const short8*)(kbase + (size_t)(16 + l15) * 256);

  for (int it = 0; it < NN / 32; it++) {
    const int nb = it * 32;
    short8 va0 = *(const short8*)(vb0 + nb);
    short8 va1 = *(const short8*)(vb1 + nb);
    f32x4 z = {0.f, 0.f, 0.f, 0.f};
    f32x4 st0 = __builtin_amdgcn_mfma_f32_16x16x32_bf16(ka0, bq, z, 0, 0, 0);
    f32x4 st1 = __builtin_amdgcn_mfma_f32_16x16x32_bf16(ka1, bq, z, 0, 0, 0);
    if (it + 1 < NN / 32) {  // prefetch next K frags
      ka0 = *(const short8*)(kbase + (size_t)(nb + 32 + l15) * 256);
      ka1 = *(const short8*)(kbase + (size_t)(nb + 48 + l15) * 256);
    }
    float p0 = __expf(st0[0]), p1 = __expf(st0[1]);
    float p2 = __expf(st0[2]), p3 = __expf(st0[3]);
    float p4 = __expf(st1[0]), p5 = __expf(st1[1]);
    float p6 = __expf(st1[2]), p7 = __expf(st1[3]);
    dsum += ((p0 + p1) + (p2 + p3)) + ((p4 + p5) + (p6 + p7));
    int* sm = &smem[it & 1][wave][0];
    *(int2*)(sm + wr0) = make_int2((int)pkrnd(p0, p1), (int)pkrnd(p2, p3));
    *(int2*)(sm + wr1) = make_int2((int)pkrnd(p4, p5), (int)pkrnd(p6, p7));
    short8 pa = *(short8*)(sm + rd);
    oacc0 = __builtin_amdgcn_mfma_f32_16x16x32_bf16(pa, va0, oacc0, 0, 0, 0);
    oacc1 = __builtin_amdgcn_mfma_f32_16x16x32_bf16(pa, va1, oacc1, 0, 0, 0);
  }

  float d = dsum;
  d += __shfl_xor(d, 16);
  d += __shfl_xor(d, 32);

  short* ob = O + ((size_t)b * HW + mBase) * 256 + head * DH + l15;
#pragma unroll
  for (int r = 0; r < 4; r++) {
    float dr = __shfl(d, quad * 4 + r);
    float inv = 1.0f / dr;
    ob[(size_t)(quad * 4 + r) * 256] = f2bf_s(oacc0[r] * inv);
    ob[(size_t)(quad * 4 + r) * 256 + 16] = f2bf_s(oacc1[r] * inv);
  }
}

// ---------------------------------------------------------------------------
// wo GEMM via MFMA with split-bf16 weights (X = attn O, bf16 m-major).
// ---------------------------------------------------------------------------
__global__ __launch_bounds__(256) void wo_gemm_mfma(const short* __restrict__ Whi,
                                                    const short* __restrict__ Wlo,
                                                    const float* __restrict__ bias,
                                                    const short* __restrict__ X,
                                                    float* __restrict__ Y) {
  const int tid = threadIdx.x;
  const int wave = tid >> 6;
  const int lane = tid & 63;
  const int quad = lane >> 4;
  const int l15 = lane & 15;
  const int b = blockIdx.z;
  const int oBase = blockIdx.y * 64 + wave * 16;
  const int mBase = blockIdx.x * 64;

  const short* wh = Whi + (size_t)(oBase + l15) * 256 + quad * 8;
  const short* wl = Wlo + (size_t)(oBase + l15) * 256 + quad * 8;
  const short* xb = X + ((size_t)b * HW + mBase) * 256 + quad * 8;

  f32x4 acc[4] = {};

  for (int k = 0; k < 256; k += 32) {
    short8 ah = *(const short8*)(wh + k);
    short8 al = *(const short8*)(wl + k);
#pragma unroll
    for (int mt = 0; mt < 4; mt++) {
      short8 bx = *(const short8*)(xb + (size_t)(mt * 16 + l15) * 256 + k);
      acc[mt] = __builtin_amdgcn_mfma_f32_16x16x32_bf16(ah, bx, acc[mt], 0, 0, 0);
      acc[mt] = __builtin_amdgcn_mfma_f32_16x16x32_bf16(al, bx, acc[mt], 0, 0, 0);
    }
  }

#pragma unroll
  for (int r = 0; r < 4; r++) {
    int o = oBase + quad * 4 + r;
    float bs = bias[o];
    float* yrow = Y + ((size_t)b * 256 + o) * HW + mBase + l15;
#pragma unroll
    for (int mt = 0; mt < 4; mt++) {
      yrow[mt * 16] = acc[mt][r] + bs;
    }
  }
}

// ---------------------------------------------------------------------------
extern "C" void kernel_launch(void* const* d_in, const int* in_sizes, int n_in,
                              void* d_out, int out_size, void* d_ws, size_t ws_size,
                              hipStream_t stream) {
  const float* x    = (const float*)d_in[0];
  const float* kv   = (const float*)d_in[1];
  const float* wq   = (const float*)d_in[2];
  const float* bq   = (const float*)d_in[3];
  const float* wk   = (const float*)d_in[4];
  const float* bk   = (const float*)d_in[5];
  const float* wv   = (const float*)d_in[6];
  const float* bv   = (const float*)d_in[7];
  const float* w_dw = (const float*)d_in[8];
  const float* b_dw = (const float*)d_in[9];
  const float* ln_w = (const float*)d_in[10];
  const float* ln_b = (const float*)d_in[11];
  const float* w_off= (const float*)d_in[12];
  const float* wo   = (const float*)d_in[13];
  const float* bo   = (const float*)d_in[14];
  float* out = (float*)d_out;
  float* ws = (float*)d_ws;

  // workspace layout (float slots):
  //   q   [0,        4718592)  : 8*256*2304 fp32
  //   R   [4718592,  7077888)  : kvs fp32 (dies after v-GEMM) overlapped
  //                              with O bf16 (born in attn)
  //   Kb  [7077888,  7667712)  : 8*576*256 bf16
  //   Vb  [7667712,  8257536)  : 8*256*576 bf16
  //   planes [8257536, 8519680): 8 x 65536 bf16
  float* q   = ws;
  float* kvs = ws + 4718592;
  short* O   = (short*)(ws + 4718592);
  short* Kb  = (short*)(ws + 7077888);
  short* Vb  = (short*)(ws + 7667712);
  short* Wqh = (short*)(ws + 8257536);
  short* Wql = Wqh + 65536;
  short* Wkh = Wql + 65536;
  short* Wkl = Wkh + 65536;
  short* Wvh = Wkl + 65536;
  short* Wvl = Wvh + 65536;
  short* Woh = Wvl + 65536;
  short* Wol = Woh + 65536;

  // split all four 256x256 weights into bf16 hi/lo
  split4<<<dim3(1024), dim3(256), 0, stream>>>(wq, wk, wv, wo, Wqh, Wql, Wkh, Wkl,
                                               Wvh, Wvl, Woh, Wol);
  // q = wq @ x + bq : fp32 (8,256,2304), 4-wave blocks
  gemm_q_mfma<<<dim3(HW / 64, BB), dim3(256), 0, stream>>>(Wqh, Wql, bq, x, q);
  // offsets + bilinear sample -> kvs fp32 (8,256,576), channel-split waves
  dw_sample_kernel<<<dim3(BH * NN / 16), dim3(64), 0, stream>>>(
      q, kv, w_dw, b_dw, ln_w, ln_b, w_off, kvs);
  // K^T bf16 (8,576,256) and V bf16 (8,256,576)
  k_gemm_mfma<<<dim3(NN / 32, 4, BB), dim3(64), 0, stream>>>(Wkh, Wkl, bk, kvs, Kb);
  gemm_axf_mfma<__hip_bfloat16><<<dim3(NN / 64, 8, BB), dim3(64), 0, stream>>>(
      Wvh, Wvl, bv, kvs, (__hip_bfloat16*)Vb, NN);
  // MFMA attention -> O bf16 (8,2304,256); kvs dead from here
  attn_mfma<<<dim3(HW / 64, BH), dim3(256), 0, stream>>>(q, Kb, Vb, O);
  // out = wo @ O + bo via split-bf16 MFMA
  wo_gemm_mfma<<<dim3(HW / 64, 4, BB), dim3(256), 0, stream>>>(Woh, Wol, bo, O, out);
}

// Round 7
// 293.715 us; speedup vs baseline: 1.0173x; 1.0173x over previous
//
#include <hip/hip_runtime.h>
#include <hip/hip_bf16.h>
#include <cstddef>

// Problem constants
#define BB 8
#define DIM 256
#define HH 48
#define WW 48
#define HW 2304        // 48*48
#define HEADS 8
#define DH 32
#define BH 64          // B*HEADS
#define HK 24
#define WK 24
#define NN 576         // HK*WK
#define SCALE 0.17677669529663687f
#define EPSF 1e-5f

typedef __attribute__((ext_vector_type(8))) short short8;
typedef __attribute__((ext_vector_type(4))) float f32x4;

static __device__ inline short f2bf_s(float f) {
  __hip_bfloat16 h = __float2bfloat16(f);
  return *reinterpret_cast<short*>(&h);
}

// pack two floats into bf16 pair (round-half-up): lo short = a, hi short = b
static __device__ inline unsigned pkrnd(float a, float b) {
  unsigned ua = __builtin_bit_cast(unsigned, a) + 0x8000u;
  unsigned ub = __builtin_bit_cast(unsigned, b) + 0x8000u;
  return __builtin_amdgcn_perm(ub, ua, 0x07060302);
}

// split 8 fp32 into bf16 hi/lo short8s (truncation split: hi+lo ~ 16-bit mant)
static __device__ inline void split8(const float* xf, short8& bh, short8& bl) {
  union { unsigned u[4]; short8 v; } H, L;
#pragma unroll
  for (int p = 0; p < 4; p++) {
    float x0 = xf[2 * p], x1 = xf[2 * p + 1];
    unsigned u0 = __builtin_bit_cast(unsigned, x0) & 0xffff0000u;
    unsigned u1 = __builtin_bit_cast(unsigned, x1) & 0xffff0000u;
    float l0 = x0 - __builtin_bit_cast(float, u0);
    float l1 = x1 - __builtin_bit_cast(float, u1);
    H.u[p] = __builtin_amdgcn_perm(u1, u0, 0x07060302);
    L.u[p] = __builtin_amdgcn_perm(__builtin_bit_cast(unsigned, l1),
                                   __builtin_bit_cast(unsigned, l0), 0x07060302);
  }
  bh = H.v;
  bl = L.v;
}

// ---------------------------------------------------------------------------
// Split 4 weight matrices (each 65536 fp32) into bf16 hi/lo planes.
// ---------------------------------------------------------------------------
__global__ __launch_bounds__(256) void split4(
    const float* __restrict__ w0, const float* __restrict__ w1,
    const float* __restrict__ w2, const float* __restrict__ w3,
    short* __restrict__ h0, short* __restrict__ l0,
    short* __restrict__ h1, short* __restrict__ l1,
    short* __restrict__ h2, short* __restrict__ l2,
    short* __restrict__ h3, short* __restrict__ l3) {
  const float* srcs[4] = {w0, w1, w2, w3};
  short* his[4] = {h0, h1, h2, h3};
  short* los[4] = {l0, l1, l2, l3};
  int sel = blockIdx.x >> 8;
  int i = (blockIdx.x & 255) * 256 + threadIdx.x;
  float v = srcs[sel][i];
  unsigned u = __builtin_bit_cast(unsigned, v) & 0xffff0000u;
  float rem = v - __builtin_bit_cast(float, u);
  his[sel][i] = (short)(u >> 16);
  los[sel][i] = (short)(__builtin_bit_cast(unsigned, rem) >> 16);
}

// ---------------------------------------------------------------------------
// Transpose+split x: (b, 256c, 2304m) fp32 -> Xt hi/lo bf16 (b, 2304m, 256c).
// 64x64 tiles via LDS. Grid (36, 4, 8), 256 threads.
// ---------------------------------------------------------------------------
__global__ __launch_bounds__(256) void xt_split(const float* __restrict__ x,
                                                short* __restrict__ Xh,
                                                short* __restrict__ Xl) {
  __shared__ float t[64][65];
  const int b = blockIdx.z, c0 = blockIdx.y * 64, m0 = blockIdx.x * 64;
  const int col = threadIdx.x & 63, row4 = threadIdx.x >> 6;
  const float* xb = x + ((size_t)b * 256 + c0) * HW + m0;
#pragma unroll
  for (int k = 0; k < 16; k++) {
    int c = row4 + k * 4;
    t[c][col] = xb[(size_t)c * HW + col];
  }
  __syncthreads();
  short* oh = Xh + ((size_t)b * HW + m0) * 256 + c0;
  short* ol = Xl + ((size_t)b * HW + m0) * 256 + c0;
#pragma unroll
  for (int k = 0; k < 16; k++) {
    int m = row4 + k * 4;
    float v = t[col][m];
    unsigned u = __builtin_bit_cast(unsigned, v) & 0xffff0000u;
    float rem = v - __builtin_bit_cast(float, u);
    oh[(size_t)m * 256 + col] = (short)(u >> 16);
    ol[(size_t)m * 256 + col] = (short)(__builtin_bit_cast(unsigned, rem) >> 16);
  }
}

// ---------------------------------------------------------------------------
// q GEMM, pure bf16 3-pass: wave w owns o-tile 64, block owns m-tile 64.
// A = Wq rows (hi/lo), B = Xt rows (hi/lo, contiguous b128). Grid (36, 8).
// ---------------------------------------------------------------------------
__global__ __launch_bounds__(256) void gemm_q_mfma(const short* __restrict__ Wh,
                                                   const short* __restrict__ Wl,
                                                   const float* __restrict__ bias,
                                                   const short* __restrict__ Xh,
                                                   const short* __restrict__ Xl,
                                                   float* __restrict__ Y) {
  const int tid = threadIdx.x;
  const int wave = tid >> 6;
  const int lane = tid & 63;
  const int quad = lane >> 4, l15 = lane & 15;
  const int b = blockIdx.y;
  const int oBase = wave * 64;
  const int mBase = blockIdx.x * 64;

  f32x4 acc[4][4] = {};
  for (int kc = 0; kc < 256; kc += 32) {
    short8 ah[4], al[4];
#pragma unroll
    for (int os = 0; os < 4; os++) {
      ah[os] = *(const short8*)(Wh + (size_t)(oBase + os * 16 + l15) * 256 + kc + quad * 8);
      al[os] = *(const short8*)(Wl + (size_t)(oBase + os * 16 + l15) * 256 + kc + quad * 8);
    }
#pragma unroll
    for (int mt = 0; mt < 4; mt++) {
      const short* xr = Xh + ((size_t)b * HW + mBase + mt * 16 + l15) * 256 + kc + quad * 8;
      const short* xrl = Xl + ((size_t)b * HW + mBase + mt * 16 + l15) * 256 + kc + quad * 8;
      short8 bh_ = *(const short8*)xr;
      short8 bl_ = *(const short8*)xrl;
#pragma unroll
      for (int os = 0; os < 4; os++) {
        acc[os][mt] = __builtin_amdgcn_mfma_f32_16x16x32_bf16(ah[os], bh_, acc[os][mt], 0, 0, 0);
        acc[os][mt] = __builtin_amdgcn_mfma_f32_16x16x32_bf16(al[os], bh_, acc[os][mt], 0, 0, 0);
        acc[os][mt] = __builtin_amdgcn_mfma_f32_16x16x32_bf16(ah[os], bl_, acc[os][mt], 0, 0, 0);
      }
    }
  }

#pragma unroll
  for (int os = 0; os < 4; os++)
#pragma unroll
    for (int r = 0; r < 4; r++) {
      int o = oBase + os * 16 + quad * 4 + r;
      float bs = bias[o];
      float* yp = Y + ((size_t)b * 256 + o) * HW + mBase + l15;
#pragma unroll
      for (int mt = 0; mt < 4; mt++) yp[mt * 16] = acc[os][mt][r] + bs;
    }
}

// ---------------------------------------------------------------------------
// dw conv + LN + GELU + offsets + bilinear sample. lane = cg*16 + nl; cg owns
// 8 channels, nl one n; reductions via shfl_xor. Writes kvsT bf16 hi/lo
// (b, n, 256c). Grid BH*NN/16 = 2304 x 64.
// ---------------------------------------------------------------------------
__global__ __launch_bounds__(64) void dw_sample_kernel(
    const float* __restrict__ q, const float* __restrict__ kv,
    const float* __restrict__ w_dw, const float* __restrict__ b_dw,
    const float* __restrict__ ln_w, const float* __restrict__ ln_b,
    const float* __restrict__ w_off, short* __restrict__ kvsTh,
    short* __restrict__ kvsTl) {
  __shared__ float s_wdw[DH * 25];
  __shared__ float s_bdw[DH], s_lnw[DH], s_lnb[DH], s_woff[2 * DH];
  const int tid = threadIdx.x;
  for (int i = tid; i < DH * 25; i += 64) s_wdw[i] = w_dw[i];
  if (tid < DH) { s_bdw[tid] = b_dw[tid]; s_lnw[tid] = ln_w[tid]; s_lnb[tid] = ln_b[tid]; }
  if (tid < 2 * DH) s_woff[tid] = w_off[tid];
  __syncthreads();

  const int nl = tid & 15, cg = tid >> 4;
  const int c0 = cg * 8;
  const int bh = blockIdx.x / (NN / 16);
  const int ntile = blockIdx.x - bh * (NN / 16);
  const int n = ntile * 16 + nl;
  const int yk = n / WK, xk = n - yk * WK;

  const float* qb = q + (size_t)bh * DH * HW;
  float t[8];
#pragma unroll
  for (int j = 0; j < 8; j++) t[j] = s_bdw[c0 + j];

  const int y0r = yk * 2 - 2, x0r = xk * 2 - 2;
  for (int dy = 0; dy < 5; dy++) {
    int y = y0r + dy;
    if (y < 0 || y >= HH) continue;
    for (int dx = 0; dx < 5; dx++) {
      int x = x0r + dx;
      if (x < 0 || x >= WW) continue;
      int off = y * WW + x;
      int widx = dy * 5 + dx;
#pragma unroll
      for (int j = 0; j < 8; j++)
        t[j] += s_wdw[(c0 + j) * 25 + widx] * qb[(size_t)(c0 + j) * HW + off];
    }
  }

  float mu = 0.f;
#pragma unroll
  for (int j = 0; j < 8; j++) mu += t[j];
  mu += __shfl_xor(mu, 16);
  mu += __shfl_xor(mu, 32);
  mu *= (1.0f / DH);
  float var = 0.f;
#pragma unroll
  for (int j = 0; j < 8; j++) { float d = t[j] - mu; var += d * d; }
  var += __shfl_xor(var, 16);
  var += __shfl_xor(var, 32);
  var *= (1.0f / DH);
  float rstd = rsqrtf(var + EPSF);

  float o0 = 0.f, o1 = 0.f;
#pragma unroll
  for (int j = 0; j < 8; j++) {
    float xn = (t[j] - mu) * rstd * s_lnw[c0 + j] + s_lnb[c0 + j];
    float g = 0.5f * xn * (1.0f + erff(xn * 0.70710678118654752f));
    o0 += s_woff[c0 + j] * g;
    o1 += s_woff[DH + c0 + j] * g;
  }
  o0 += __shfl_xor(o0, 16);
  o0 += __shfl_xor(o0, 32);
  o1 += __shfl_xor(o1, 16);
  o1 += __shfl_xor(o1, 32);

  const float ref_y = (0.5f + (float)yk) / 23.0f * 2.0f - 1.0f;
  const float ref_x = (0.5f + (float)xk) / 23.0f * 2.0f - 1.0f;
  float py = fminf(fmaxf(o0 + ref_y, -1.0f), 1.0f);
  float px = fminf(fmaxf(o1 + ref_x, -1.0f), 1.0f);

  float gx = (px + 1.0f) * 0.5f * 47.0f;
  float gy = (py + 1.0f) * 0.5f * 47.0f;
  float x0f = floorf(gx), y0f = floorf(gy);
  float wx = gx - x0f, wy = gy - y0f;
  int x0 = (int)x0f, y0 = (int)y0f;
  int x0i = min(max(x0, 0), WW - 1);
  int x1i = min(max(x0 + 1, 0), WW - 1);
  int y0i = min(max(y0, 0), HH - 1);
  int y1i = min(max(y0 + 1, 0), HH - 1);
  float w00 = (1.f - wx) * (1.f - wy);
  float w01 = wx * (1.f - wy);
  float w10 = (1.f - wx) * wy;
  float w11 = wx * wy;
  int i00 = y0i * WW + x0i, i01 = y0i * WW + x1i;
  int i10 = y1i * WW + x0i, i11 = y1i * WW + x1i;

  const float* kvb = kv + ((size_t)bh * DH + c0) * HW;
  float val[8];
#pragma unroll
  for (int j = 0; j < 8; j++) {
    const float* p = kvb + (size_t)j * HW;
    val[j] = w00 * p[i00] + w01 * p[i01] + w10 * p[i10] + w11 * p[i11];
  }
  short8 hv, lv;
  split8(val, hv, lv);
  size_t idx = ((size_t)(bh >> 3) * NN + n) * 256 + (bh & 7) * DH + c0;
  *(short8*)(kvsTh + idx) = hv;
  *(short8*)(kvsTl + idx) = lv;
}

// ---------------------------------------------------------------------------
// Fused K/V GEMM, pure bf16 3-pass from kvsT (b,n,256) hi/lo.
// mode = blockIdx.y>>2: 0 -> K^T (b,n,256o); 1 -> V (b,256o,n).
// Grid (9, 8, 8), 256 threads.
// ---------------------------------------------------------------------------
__global__ __launch_bounds__(256) void kv_gemm_mfma(
    const short* __restrict__ Wkh, const short* __restrict__ Wkl,
    const float* __restrict__ bk,
    const short* __restrict__ Wvh, const short* __restrict__ Wvl,
    const float* __restrict__ bv,
    const short* __restrict__ Xh, const short* __restrict__ Xl,
    short* __restrict__ Kb, short* __restrict__ Vb) {
  const int tid = threadIdx.x;
  const int wave = tid >> 6;
  const int lane = tid & 63;
  const int quad = lane >> 4, l15 = lane & 15;
  const int b = blockIdx.z;
  const int mode = blockIdx.y >> 2;
  const int oTile = (blockIdx.y & 3) * 64;
  const int nBase = blockIdx.x * 64;

  if (mode == 0) {
    // D[n][o]: A = kvsT rows n (wave: 16 n), B = Wk rows o (4 tiles x 16)
    const int nW = nBase + wave * 16;
    const short* ارow = nullptr; (void)ارow;
    const short* arh = Xh + ((size_t)b * NN + nW + l15) * 256 + quad * 8;
    const short* arl = Xl + ((size_t)b * NN + nW + l15) * 256 + quad * 8;
    f32x4 acc[4] = {};
    for (int kc = 0; kc < 256; kc += 32) {
      short8 ah = *(const short8*)(arh + kc);
      short8 al = *(const short8*)(arl + kc);
#pragma unroll
      for (int ot = 0; ot < 4; ot++) {
        short8 bh_ = *(const short8*)(Wkh + (size_t)(oTile + ot * 16 + l15) * 256 + kc + quad * 8);
        short8 bl_ = *(const short8*)(Wkl + (size_t)(oTile + ot * 16 + l15) * 256 + kc + quad * 8);
        acc[ot] = __builtin_amdgcn_mfma_f32_16x16x32_bf16(ah, bh_, acc[ot], 0, 0, 0);
        acc[ot] = __builtin_amdgcn_mfma_f32_16x16x32_bf16(al, bh_, acc[ot], 0, 0, 0);
        acc[ot] = __builtin_amdgcn_mfma_f32_16x16x32_bf16(ah, bl_, acc[ot], 0, 0, 0);
      }
    }
    float bs[4];
#pragma unroll
    for (int ot = 0; ot < 4; ot++) bs[ot] = bk[oTile + ot * 16 + l15];
#pragma unroll
    for (int r = 0; r < 4; r++) {
      short* yp = Kb + ((size_t)b * NN + nW + quad * 4 + r) * 256 + oTile + l15;
#pragma unroll
      for (int ot = 0; ot < 4; ot++) yp[ot * 16] = f2bf_s(acc[ot][r] + bs[ot]);
    }
  } else {
    // D[o][n]: A = Wv rows (wave: 16 o), B = kvsT rows n (4 tiles x 16)
    const int oW = oTile + wave * 16;
    const short* arh = Wvh + (size_t)(oW + l15) * 256 + quad * 8;
    const short* arl = Wvl + (size_t)(oW + l15) * 256 + quad * 8;
    f32x4 acc[4] = {};
    for (int kc = 0; kc < 256; kc += 32) {
      short8 ah = *(const short8*)(arh + kc);
      short8 al = *(const short8*)(arl + kc);
#pragma unroll
      for (int nt = 0; nt < 4; nt++) {
        short8 bh_ = *(const short8*)(Xh + ((size_t)b * NN + nBase + nt * 16 + l15) * 256 + kc + quad * 8);
        short8 bl_ = *(const short8*)(Xl + ((size_t)b * NN + nBase + nt * 16 + l15) * 256 + kc + quad * 8);
        acc[nt] = __builtin_amdgcn_mfma_f32_16x16x32_bf16(ah, bh_, acc[nt], 0, 0, 0);
        acc[nt] = __builtin_amdgcn_mfma_f32_16x16x32_bf16(al, bh_, acc[nt], 0, 0, 0);
        acc[nt] = __builtin_amdgcn_mfma_f32_16x16x32_bf16(ah, bl_, acc[nt], 0, 0, 0);
      }
    }
#pragma unroll
    for (int r = 0; r < 4; r++) {
      int o = oW + quad * 4 + r;
      float bs = bv[o];
      short* yp = Vb + ((size_t)b * 256 + o) * NN + nBase + l15;
#pragma unroll
      for (int nt = 0; nt < 4; nt++) yp[nt * 16] = f2bf_s(acc[nt][r] + bs);
    }
  }
}

// ---------------------------------------------------------------------------
// MFMA attention v6: mt=2 (32 m/wave), fixed swizzle ((l15>>1)&3), PV deferred
// one iteration (software pipeline through double-buffered wave-private LDS).
// Grid (HW/128 = 18, 64 bh), 256 threads.
// ---------------------------------------------------------------------------
__global__ __launch_bounds__(256) void attn_mfma(const float* __restrict__ q,
                                                 const short* __restrict__ Kb,
                                                 const short* __restrict__ Vb,
                                                 short* __restrict__ O) {
  __shared__ int smem[2][4][2][256];
  const int tid = threadIdx.x;
  const int wave = tid >> 6;
  const int lane = tid & 63;
  const int quad = lane >> 4;
  const int l15 = lane & 15;
  const int bh = blockIdx.y;
  const int b = bh >> 3, head = bh & 7;
  const int mBase = blockIdx.x * 128 + wave * 32;

  short8 bq[2];
#pragma unroll
  for (int mt = 0; mt < 2; mt++) {
    const float* qp = q + ((size_t)bh * DH + quad * 8) * HW + mBase + mt * 16 + l15;
    short8 v;
#pragma unroll
    for (int j = 0; j < 8; j++) v[j] = f2bf_s(qp[(size_t)j * HW] * SCALE);
    bq[mt] = v;
  }

  const short* kbase = Kb + (size_t)b * NN * 256 + head * DH + quad * 8;
  const short* vb0 = Vb + ((size_t)b * 256 + head * DH + l15) * NN + quad * 8;
  const short* vb1 = vb0 + (size_t)16 * NN;

  f32x4 oacc[2][2] = {};
  float dsum[2] = {0.f, 0.f};

  const int g = (l15 >> 1) & 3;
  const int row16 = l15 * 16;
  const int wr0 = row16 + (((quad >> 1) ^ g) << 2) + ((quad & 1) << 1);
  const int wr1 = row16 + (((2 + (quad >> 1)) ^ g) << 2) + ((quad & 1) << 1);
  const int rd = row16 + ((quad ^ g) << 2);

  short8 ka0 = *(const short8*)(kbase + (size_t)l15 * 256);
  short8 ka1 = *(const short8*)(kbase + (size_t)(16 + l15) * 256);
  short8 va0 = *(const short8*)(vb0);
  short8 va1 = *(const short8*)(vb1);

  // ---- iteration 0: QK + exp + write buf0
  {
    f32x4 z = {0.f, 0.f, 0.f, 0.f};
    f32x4 st[2][2];
    st[0][0] = __builtin_amdgcn_mfma_f32_16x16x32_bf16(ka0, bq[0], z, 0, 0, 0);
    st[0][1] = __builtin_amdgcn_mfma_f32_16x16x32_bf16(ka1, bq[0], z, 0, 0, 0);
    st[1][0] = __builtin_amdgcn_mfma_f32_16x16x32_bf16(ka0, bq[1], z, 0, 0, 0);
    st[1][1] = __builtin_amdgcn_mfma_f32_16x16x32_bf16(ka1, bq[1], z, 0, 0, 0);
    ka0 = *(const short8*)(kbase + (size_t)(32 + l15) * 256);
    ka1 = *(const short8*)(kbase + (size_t)(48 + l15) * 256);
    int* sm = &smem[0][wave][0][0];
#pragma unroll
    for (int mt = 0; mt < 2; mt++) {
      float p0 = __expf(st[mt][0][0]), p1 = __expf(st[mt][0][1]);
      float p2 = __expf(st[mt][0][2]), p3 = __expf(st[mt][0][3]);
      float p4 = __expf(st[mt][1][0]), p5 = __expf(st[mt][1][1]);
      float p6 = __expf(st[mt][1][2]), p7 = __expf(st[mt][1][3]);
      dsum[mt] += ((p0 + p1) + (p2 + p3)) + ((p4 + p5) + (p6 + p7));
      int* base = sm + mt * 256;
      *(int2*)(base + wr0) = make_int2((int)pkrnd(p0, p1), (int)pkrnd(p2, p3));
      *(int2*)(base + wr1) = make_int2((int)pkrnd(p4, p5), (int)pkrnd(p6, p7));
    }
  }

  // ---- main loop: PV(it-1) overlapped with QK/exp(it)
  for (int it = 1; it < NN / 32; it++) {
    const int nb = it * 32;
    int* smPrev = &smem[(it + 1) & 1][wave][0][0];
    short8 pa0 = *(short8*)(smPrev + rd);
    short8 pa1 = *(short8*)(smPrev + 256 + rd);
    short8 ua0 = va0, ua1 = va1;
    va0 = *(const short8*)(vb0 + nb);
    va1 = *(const short8*)(vb1 + nb);
    f32x4 z = {0.f, 0.f, 0.f, 0.f};
    f32x4 st[2][2];
    st[0][0] = __builtin_amdgcn_mfma_f32_16x16x32_bf16(ka0, bq[0], z, 0, 0, 0);
    st[0][1] = __builtin_amdgcn_mfma_f32_16x16x32_bf16(ka1, bq[0], z, 0, 0, 0);
    st[1][0] = __builtin_amdgcn_mfma_f32_16x16x32_bf16(ka0, bq[1], z, 0, 0, 0);
    st[1][1] = __builtin_amdgcn_mfma_f32_16x16x32_bf16(ka1, bq[1], z, 0, 0, 0);
    if (it + 1 < NN / 32) {
      ka0 = *(const short8*)(kbase + (size_t)(nb + 32 + l15) * 256);
      ka1 = *(const short8*)(kbase + (size_t)(nb + 48 + l15) * 256);
    }
    oacc[0][0] = __builtin_amdgcn_mfma_f32_16x16x32_bf16(pa0, ua0, oacc[0][0], 0, 0, 0);
    oacc[0][1] = __builtin_amdgcn_mfma_f32_16x16x32_bf16(pa0, ua1, oacc[0][1], 0, 0, 0);
    oacc[1][0] = __builtin_amdgcn_mfma_f32_16x16x32_bf16(pa1, ua0, oacc[1][0], 0, 0, 0);
    oacc[1][1] = __builtin_amdgcn_mfma_f32_16x16x32_bf16(pa1, ua1, oacc[1][1], 0, 0, 0);
    int* sm = &smem[it & 1][wave][0][0];
#pragma unroll
    for (int mt = 0; mt < 2; mt++) {
      float p0 = __expf(st[mt][0][0]), p1 = __expf(st[mt][0][1]);
      float p2 = __expf(st[mt][0][2]), p3 = __expf(st[mt][0][3]);
      float p4 = __expf(st[mt][1][0]), p5 = __expf(st[mt][1][1]);
      float p6 = __expf(st[mt][1][2]), p7 = __expf(st[mt][1][3]);
      dsum[mt] += ((p0 + p1) + (p2 + p3)) + ((p4 + p5) + (p6 + p7));
      int* base = sm + mt * 256;
      *(int2*)(base + wr0) = make_int2((int)pkrnd(p0, p1), (int)pkrnd(p2, p3));
      *(int2*)(base + wr1) = make_int2((int)pkrnd(p4, p5), (int)pkrnd(p6, p7));
    }
  }

  // ---- epilogue: PV for the last tile
  {
    int* smPrev = &smem[(NN / 32 - 1) & 1][wave][0][0];
    short8 pa0 = *(short8*)(smPrev + rd);
    short8 pa1 = *(short8*)(smPrev + 256 + rd);
    oacc[0][0] = __builtin_amdgcn_mfma_f32_16x16x32_bf16(pa0, va0, oacc[0][0], 0, 0, 0);
    oacc[0][1] = __builtin_amdgcn_mfma_f32_16x16x32_bf16(pa0, va1, oacc[0][1], 0, 0, 0);
    oacc[1][0] = __builtin_amdgcn_mfma_f32_16x16x32_bf16(pa1, va0, oacc[1][0], 0, 0, 0);
    oacc[1][1] = __builtin_amdgcn_mfma_f32_16x16x32_bf16(pa1, va1, oacc[1][1], 0, 0, 0);
  }

#pragma unroll
  for (int mt = 0; mt < 2; mt++) {
    float d = dsum[mt];
    d += __shfl_xor(d, 16);
    d += __shfl_xor(d, 32);
    short* ob = O + ((size_t)b * HW + mBase + mt * 16) * 256 + head * DH + l15;
#pragma unroll
    for (int r = 0; r < 4; r++) {
      float dr = __shfl(d, quad * 4 + r);
      float inv = 1.0f / dr;
      ob[(size_t)(quad * 4 + r) * 256] = f2bf_s(oacc[mt][0][r] * inv);
      ob[(size_t)(quad * 4 + r) * 256 + 16] = f2bf_s(oacc[mt][1][r] * inv);
    }
  }
}

// ---------------------------------------------------------------------------
// wo GEMM via MFMA with split-bf16 weights (X = attn O, bf16 m-major).
// ---------------------------------------------------------------------------
__global__ __launch_bounds__(256) void wo_gemm_mfma(const short* __restrict__ Whi,
                                                    const short* __restrict__ Wlo,
                                                    const float* __restrict__ bias,
                                                    const short* __restrict__ X,
                                                    float* __restrict__ Y) {
  const int tid = threadIdx.x;
  const int wave = tid >> 6;
  const int lane = tid & 63;
  const int quad = lane >> 4;
  const int l15 = lane & 15;
  const int b = blockIdx.z;
  const int oBase = blockIdx.y * 64 + wave * 16;
  const int mBase = blockIdx.x * 64;

  const short* wh = Whi + (size_t)(oBase + l15) * 256 + quad * 8;
  const short* wl = Wlo + (size_t)(oBase + l15) * 256 + quad * 8;
  const short* xb = X + ((size_t)b * HW + mBase) * 256 + quad * 8;

  f32x4 acc[4] = {};

  for (int k = 0; k < 256; k += 32) {
    short8 ah = *(const short8*)(wh + k);
    short8 al = *(const short8*)(wl + k);
#pragma unroll
    for (int mt = 0; mt < 4; mt++) {
      short8 bx = *(const short8*)(xb + (size_t)(mt * 16 + l15) * 256 + k);
      acc[mt] = __builtin_amdgcn_mfma_f32_16x16x32_bf16(ah, bx, acc[mt], 0, 0, 0);
      acc[mt] = __builtin_amdgcn_mfma_f32_16x16x32_bf16(al, bx, acc[mt], 0, 0, 0);
    }
  }

#pragma unroll
  for (int r = 0; r < 4; r++) {
    int o = oBase + quad * 4 + r;
    float bs = bias[o];
    float* yrow = Y + ((size_t)b * 256 + o) * HW + mBase + l15;
#pragma unroll
    for (int mt = 0; mt < 4; mt++) {
      yrow[mt * 16] = acc[mt][r] + bs;
    }
  }
}

// ---------------------------------------------------------------------------
extern "C" void kernel_launch(void* const* d_in, const int* in_sizes, int n_in,
                              void* d_out, int out_size, void* d_ws, size_t ws_size,
                              hipStream_t stream) {
  const float* x    = (const float*)d_in[0];
  const float* kv   = (const float*)d_in[1];
  const float* wq   = (const float*)d_in[2];
  const float* bq   = (const float*)d_in[3];
  const float* wk   = (const float*)d_in[4];
  const float* bk   = (const float*)d_in[5];
  const float* wv   = (const float*)d_in[6];
  const float* bv   = (const float*)d_in[7];
  const float* w_dw = (const float*)d_in[8];
  const float* b_dw = (const float*)d_in[9];
  const float* ln_w = (const float*)d_in[10];
  const float* ln_b = (const float*)d_in[11];
  const float* w_off= (const float*)d_in[12];
  const float* wo   = (const float*)d_in[13];
  const float* bo   = (const float*)d_in[14];
  float* out = (float*)d_out;
  float* ws = (float*)d_ws;

  // workspace (float slots), lifetimes:
  //   q     [0,        4718592)  fp32, born gemm_q, dies after attn
  //   Xth/O [4718592,  7077888)  Xth dies after gemm_q; O born in attn
  //   Xtl   [7077888,  9437184)  dies after gemm_q; then:
  //     kvsTh [7077888, 7667712), kvsTl [7667712, 8257536)  (dw -> kv_gemm)
  //     Kb    [8257536, 8847360), Vb    [8847360, 9437184)  (kv_gemm -> attn)
  //   planes [9437184, 9699328)  8 x 65536 bf16
  // total 9699328 f = 38.8 MB
  float* q     = ws;
  short* Xth   = (short*)(ws + 4718592);
  short* O     = (short*)(ws + 4718592);
  short* Xtl   = (short*)(ws + 7077888);
  short* kvsTh = (short*)(ws + 7077888);
  short* kvsTl = (short*)(ws + 7667712);
  short* Kb    = (short*)(ws + 8257536);
  short* Vb    = (short*)(ws + 8847360);
  short* Wqh   = (short*)(ws + 9437184);
  short* Wql = Wqh + 65536;
  short* Wkh = Wql + 65536;
  short* Wkl = Wkh + 65536;
  short* Wvh = Wkl + 65536;
  short* Wvl = Wvh + 65536;
  short* Woh = Wvl + 65536;
  short* Wol = Woh + 65536;

  split4<<<dim3(1024), dim3(256), 0, stream>>>(wq, wk, wv, wo, Wqh, Wql, Wkh, Wkl,
                                               Wvh, Wvl, Woh, Wol);
  xt_split<<<dim3(HW / 64, 4, BB), dim3(256), 0, stream>>>(x, Xth, Xtl);
  gemm_q_mfma<<<dim3(HW / 64, BB), dim3(256), 0, stream>>>(Wqh, Wql, bq, Xth, Xtl, q);
  dw_sample_kernel<<<dim3(BH * NN / 16), dim3(64), 0, stream>>>(
      q, kv, w_dw, b_dw, ln_w, ln_b, w_off, kvsTh, kvsTl);
  kv_gemm_mfma<<<dim3(NN / 64, 8, BB), dim3(256), 0, stream>>>(
      Wkh, Wkl, bk, Wvh, Wvl, bv, kvsTh, kvsTl, Kb, Vb);
  attn_mfma<<<dim3(HW / 128, BH), dim3(256), 0, stream>>>(q, Kb, Vb, O);
  wo_gemm_mfma<<<dim3(HW / 64, 4, BB), dim3(256), 0, stream>>>(Woh, Wol, bo, O, out);
}

// Round 8
// 261.186 us; speedup vs baseline: 1.1440x; 1.1245x over previous
//
#include <hip/hip_runtime.h>
#include <hip/hip_bf16.h>
#include <cstddef>

// Problem constants
#define BB 8
#define DIM 256
#define HH 48
#define WW 48
#define HW 2304        // 48*48
#define HEADS 8
#define DH 32
#define BH 64          // B*HEADS
#define HK 24
#define WK 24
#define NN 576         // HK*WK
#define SCALE 0.17677669529663687f
#define EPSF 1e-5f

typedef __attribute__((ext_vector_type(8))) short short8;
typedef __attribute__((ext_vector_type(4))) float f32x4;

static __device__ inline short f2bf_s(float f) {
  __hip_bfloat16 h = __float2bfloat16(f);
  return *reinterpret_cast<short*>(&h);
}

// pack two floats into bf16 pair (round-half-up): lo short = a, hi short = b
static __device__ inline unsigned pkrnd(float a, float b) {
  unsigned ua = __builtin_bit_cast(unsigned, a) + 0x8000u;
  unsigned ub = __builtin_bit_cast(unsigned, b) + 0x8000u;
  return __builtin_amdgcn_perm(ub, ua, 0x07060302);
}

// split 8 fp32 into bf16 hi/lo short8s (truncation split)
static __device__ inline void split8(const float* xf, short8& bh, short8& bl) {
  union { unsigned u[4]; short8 v; } H, L;
#pragma unroll
  for (int p = 0; p < 4; p++) {
    float x0 = xf[2 * p], x1 = xf[2 * p + 1];
    unsigned u0 = __builtin_bit_cast(unsigned, x0) & 0xffff0000u;
    unsigned u1 = __builtin_bit_cast(unsigned, x1) & 0xffff0000u;
    float l0 = x0 - __builtin_bit_cast(float, u0);
    float l1 = x1 - __builtin_bit_cast(float, u1);
    H.u[p] = __builtin_amdgcn_perm(u1, u0, 0x07060302);
    L.u[p] = __builtin_amdgcn_perm(__builtin_bit_cast(unsigned, l1),
                                   __builtin_bit_cast(unsigned, l0), 0x07060302);
  }
  bh = H.v;
  bl = L.v;
}

// ---------------------------------------------------------------------------
// prep: blocks [0,1152) transpose+split x into Xt hi/lo bf16 (b, m, 256c);
// blocks [1152,1408) split the four 256x256 weights into bf16 hi/lo planes.
// ---------------------------------------------------------------------------
__global__ __launch_bounds__(256) void prep(
    const float* __restrict__ x,
    const float* __restrict__ wq, const float* __restrict__ wk,
    const float* __restrict__ wv, const float* __restrict__ wo,
    short* __restrict__ Xh, short* __restrict__ Xl,
    short* __restrict__ Wqh, short* __restrict__ Wql,
    short* __restrict__ Wkh, short* __restrict__ Wkl,
    short* __restrict__ Wvh, short* __restrict__ Wvl,
    short* __restrict__ Woh, short* __restrict__ Wol) {
  const int bid = blockIdx.x;
  if (bid < 1152) {
    __shared__ float t[64][65];
    int mt = bid % 36, t2 = bid / 36;
    int ct = t2 & 3, b = t2 >> 2;
    const int c0 = ct * 64, m0 = mt * 64;
    const int col = threadIdx.x & 63, row4 = threadIdx.x >> 6;
    const float* xb = x + ((size_t)b * 256 + c0) * HW + m0;
#pragma unroll
    for (int k = 0; k < 16; k++) {
      int c = row4 + k * 4;
      t[c][col] = xb[(size_t)c * HW + col];
    }
    __syncthreads();
    short* oh = Xh + ((size_t)b * HW + m0) * 256 + c0;
    short* ol = Xl + ((size_t)b * HW + m0) * 256 + c0;
#pragma unroll
    for (int k = 0; k < 16; k++) {
      int m = row4 + k * 4;
      float v = t[col][m];
      unsigned u = __builtin_bit_cast(unsigned, v) & 0xffff0000u;
      float rem = v - __builtin_bit_cast(float, u);
      oh[(size_t)m * 256 + col] = (short)(u >> 16);
      ol[(size_t)m * 256 + col] = (short)(__builtin_bit_cast(unsigned, rem) >> 16);
    }
  } else {
    const float* srcs[4] = {wq, wk, wv, wo};
    short* his[4] = {Wqh, Wkh, Wvh, Woh};
    short* los[4] = {Wql, Wkl, Wvl, Wol};
    int e0 = (bid - 1152) * 1024 + threadIdx.x * 4;
    int w = e0 >> 16, off = e0 & 65535;
    float4 v4 = *(const float4*)(srcs[w] + off);
    float vv[4] = {v4.x, v4.y, v4.z, v4.w};
    union { short s[4]; int2 i2; } Hu, Lu;
#pragma unroll
    for (int j = 0; j < 4; j++) {
      unsigned u = __builtin_bit_cast(unsigned, vv[j]) & 0xffff0000u;
      float rem = vv[j] - __builtin_bit_cast(float, u);
      Hu.s[j] = (short)(u >> 16);
      Lu.s[j] = (short)(__builtin_bit_cast(unsigned, rem) >> 16);
    }
    *(int2*)(his[w] + off) = Hu.i2;
    *(int2*)(los[w] + off) = Lu.i2;
  }
}

// ---------------------------------------------------------------------------
// q GEMM, pure bf16 3-pass: wave w owns o-tile 64, block owns m-tile 64.
// Grid (36, 8), 256 threads.
// ---------------------------------------------------------------------------
__global__ __launch_bounds__(256) void gemm_q_mfma(const short* __restrict__ Wh,
                                                   const short* __restrict__ Wl,
                                                   const float* __restrict__ bias,
                                                   const short* __restrict__ Xh,
                                                   const short* __restrict__ Xl,
                                                   float* __restrict__ Y) {
  const int tid = threadIdx.x;
  const int wave = tid >> 6;
  const int lane = tid & 63;
  const int quad = lane >> 4, l15 = lane & 15;
  const int b = blockIdx.y;
  const int oBase = wave * 64;
  const int mBase = blockIdx.x * 64;

  f32x4 acc[4][4] = {};
  for (int kc = 0; kc < 256; kc += 32) {
    short8 ah[4], al[4];
#pragma unroll
    for (int os = 0; os < 4; os++) {
      ah[os] = *(const short8*)(Wh + (size_t)(oBase + os * 16 + l15) * 256 + kc + quad * 8);
      al[os] = *(const short8*)(Wl + (size_t)(oBase + os * 16 + l15) * 256 + kc + quad * 8);
    }
#pragma unroll
    for (int mt = 0; mt < 4; mt++) {
      short8 bh_ = *(const short8*)(Xh + ((size_t)b * HW + mBase + mt * 16 + l15) * 256 + kc + quad * 8);
      short8 bl_ = *(const short8*)(Xl + ((size_t)b * HW + mBase + mt * 16 + l15) * 256 + kc + quad * 8);
#pragma unroll
      for (int os = 0; os < 4; os++) {
        acc[os][mt] = __builtin_amdgcn_mfma_f32_16x16x32_bf16(ah[os], bh_, acc[os][mt], 0, 0, 0);
        acc[os][mt] = __builtin_amdgcn_mfma_f32_16x16x32_bf16(al[os], bh_, acc[os][mt], 0, 0, 0);
        acc[os][mt] = __builtin_amdgcn_mfma_f32_16x16x32_bf16(ah[os], bl_, acc[os][mt], 0, 0, 0);
      }
    }
  }

#pragma unroll
  for (int os = 0; os < 4; os++)
#pragma unroll
    for (int r = 0; r < 4; r++) {
      int o = oBase + os * 16 + quad * 4 + r;
      float bs = bias[o];
      float* yp = Y + ((size_t)b * 256 + o) * HW + mBase + l15;
#pragma unroll
      for (int mt = 0; mt < 4; mt++) yp[mt * 16] = acc[os][mt][r] + bs;
    }
}

// ---------------------------------------------------------------------------
// dw conv + LN + GELU + offsets + bilinear sample. Writes kvsT bf16 hi/lo
// (b, n, 256c). Grid BH*NN/16 = 2304 x 64.
// ---------------------------------------------------------------------------
__global__ __launch_bounds__(64) void dw_sample_kernel(
    const float* __restrict__ q, const float* __restrict__ kv,
    const float* __restrict__ w_dw, const float* __restrict__ b_dw,
    const float* __restrict__ ln_w, const float* __restrict__ ln_b,
    const float* __restrict__ w_off, short* __restrict__ kvsTh,
    short* __restrict__ kvsTl) {
  __shared__ float s_wdw[DH * 25];
  __shared__ float s_bdw[DH], s_lnw[DH], s_lnb[DH], s_woff[2 * DH];
  const int tid = threadIdx.x;
  for (int i = tid; i < DH * 25; i += 64) s_wdw[i] = w_dw[i];
  if (tid < DH) { s_bdw[tid] = b_dw[tid]; s_lnw[tid] = ln_w[tid]; s_lnb[tid] = ln_b[tid]; }
  if (tid < 2 * DH) s_woff[tid] = w_off[tid];
  __syncthreads();

  const int nl = tid & 15, cg = tid >> 4;
  const int c0 = cg * 8;
  const int bh = blockIdx.x / (NN / 16);
  const int ntile = blockIdx.x - bh * (NN / 16);
  const int n = ntile * 16 + nl;
  const int yk = n / WK, xk = n - yk * WK;

  const float* qb = q + (size_t)bh * DH * HW;
  float t[8];
#pragma unroll
  for (int j = 0; j < 8; j++) t[j] = s_bdw[c0 + j];

  const int y0r = yk * 2 - 2, x0r = xk * 2 - 2;
  for (int dy = 0; dy < 5; dy++) {
    int y = y0r + dy;
    if (y < 0 || y >= HH) continue;
    for (int dx = 0; dx < 5; dx++) {
      int x = x0r + dx;
      if (x < 0 || x >= WW) continue;
      int off = y * WW + x;
      int widx = dy * 5 + dx;
#pragma unroll
      for (int j = 0; j < 8; j++)
        t[j] += s_wdw[(c0 + j) * 25 + widx] * qb[(size_t)(c0 + j) * HW + off];
    }
  }

  float mu = 0.f;
#pragma unroll
  for (int j = 0; j < 8; j++) mu += t[j];
  mu += __shfl_xor(mu, 16);
  mu += __shfl_xor(mu, 32);
  mu *= (1.0f / DH);
  float var = 0.f;
#pragma unroll
  for (int j = 0; j < 8; j++) { float d = t[j] - mu; var += d * d; }
  var += __shfl_xor(var, 16);
  var += __shfl_xor(var, 32);
  var *= (1.0f / DH);
  float rstd = rsqrtf(var + EPSF);

  float o0 = 0.f, o1 = 0.f;
#pragma unroll
  for (int j = 0; j < 8; j++) {
    float xn = (t[j] - mu) * rstd * s_lnw[c0 + j] + s_lnb[c0 + j];
    float g = 0.5f * xn * (1.0f + erff(xn * 0.70710678118654752f));
    o0 += s_woff[c0 + j] * g;
    o1 += s_woff[DH + c0 + j] * g;
  }
  o0 += __shfl_xor(o0, 16);
  o0 += __shfl_xor(o0, 32);
  o1 += __shfl_xor(o1, 16);
  o1 += __shfl_xor(o1, 32);

  const float ref_y = (0.5f + (float)yk) / 23.0f * 2.0f - 1.0f;
  const float ref_x = (0.5f + (float)xk) / 23.0f * 2.0f - 1.0f;
  float py = fminf(fmaxf(o0 + ref_y, -1.0f), 1.0f);
  float px = fminf(fmaxf(o1 + ref_x, -1.0f), 1.0f);

  float gx = (px + 1.0f) * 0.5f * 47.0f;
  float gy = (py + 1.0f) * 0.5f * 47.0f;
  float x0f = floorf(gx), y0f = floorf(gy);
  float wx = gx - x0f, wy = gy - y0f;
  int x0 = (int)x0f, y0 = (int)y0f;
  int x0i = min(max(x0, 0), WW - 1);
  int x1i = min(max(x0 + 1, 0), WW - 1);
  int y0i = min(max(y0, 0), HH - 1);
  int y1i = min(max(y0 + 1, 0), HH - 1);
  float w00 = (1.f - wx) * (1.f - wy);
  float w01 = wx * (1.f - wy);
  float w10 = (1.f - wx) * wy;
  float w11 = wx * wy;
  int i00 = y0i * WW + x0i, i01 = y0i * WW + x1i;
  int i10 = y1i * WW + x0i, i11 = y1i * WW + x1i;

  const float* kvb = kv + ((size_t)bh * DH + c0) * HW;
  float val[8];
#pragma unroll
  for (int j = 0; j < 8; j++) {
    const float* p = kvb + (size_t)j * HW;
    val[j] = w00 * p[i00] + w01 * p[i01] + w10 * p[i10] + w11 * p[i11];
  }
  short8 hv, lv;
  split8(val, hv, lv);
  size_t idx = ((size_t)(bh >> 3) * NN + n) * 256 + (bh & 7) * DH + c0;
  *(short8*)(kvsTh + idx) = hv;
  *(short8*)(kvsTl + idx) = lv;
}

// ---------------------------------------------------------------------------
// Fused K/V GEMM, pure bf16 3-pass from kvsT (b,n,256) hi/lo.
// mode = blockIdx.y>>2: 0 -> K^T (b,n,256o); 1 -> V (b,256o,n).
// Grid (9, 8, 8), 256 threads.
// ---------------------------------------------------------------------------
__global__ __launch_bounds__(256) void kv_gemm_mfma(
    const short* __restrict__ Wkh, const short* __restrict__ Wkl,
    const float* __restrict__ bk,
    const short* __restrict__ Wvh, const short* __restrict__ Wvl,
    const float* __restrict__ bv,
    const short* __restrict__ Xh, const short* __restrict__ Xl,
    short* __restrict__ Kb, short* __restrict__ Vb) {
  const int tid = threadIdx.x;
  const int wave = tid >> 6;
  const int lane = tid & 63;
  const int quad = lane >> 4, l15 = lane & 15;
  const int b = blockIdx.z;
  const int mode = blockIdx.y >> 2;
  const int oTile = (blockIdx.y & 3) * 64;
  const int nBase = blockIdx.x * 64;

  if (mode == 0) {
    const int nW = nBase + wave * 16;
    const short* arh = Xh + ((size_t)b * NN + nW + l15) * 256 + quad * 8;
    const short* arl = Xl + ((size_t)b * NN + nW + l15) * 256 + quad * 8;
    f32x4 acc[4] = {};
    for (int kc = 0; kc < 256; kc += 32) {
      short8 ah = *(const short8*)(arh + kc);
      short8 al = *(const short8*)(arl + kc);
#pragma unroll
      for (int ot = 0; ot < 4; ot++) {
        short8 bh_ = *(const short8*)(Wkh + (size_t)(oTile + ot * 16 + l15) * 256 + kc + quad * 8);
        short8 bl_ = *(const short8*)(Wkl + (size_t)(oTile + ot * 16 + l15) * 256 + kc + quad * 8);
        acc[ot] = __builtin_amdgcn_mfma_f32_16x16x32_bf16(ah, bh_, acc[ot], 0, 0, 0);
        acc[ot] = __builtin_amdgcn_mfma_f32_16x16x32_bf16(al, bh_, acc[ot], 0, 0, 0);
        acc[ot] = __builtin_amdgcn_mfma_f32_16x16x32_bf16(ah, bl_, acc[ot], 0, 0, 0);
      }
    }
    float bs[4];
#pragma unroll
    for (int ot = 0; ot < 4; ot++) bs[ot] = bk[oTile + ot * 16 + l15];
#pragma unroll
    for (int r = 0; r < 4; r++) {
      short* yp = Kb + ((size_t)b * NN + nW + quad * 4 + r) * 256 + oTile + l15;
#pragma unroll
      for (int ot = 0; ot < 4; ot++) yp[ot * 16] = f2bf_s(acc[ot][r] + bs[ot]);
    }
  } else {
    const int oW = oTile + wave * 16;
    const short* arh = Wvh + (size_t)(oW + l15) * 256 + quad * 8;
    const short* arl = Wvl + (size_t)(oW + l15) * 256 + quad * 8;
    f32x4 acc[4] = {};
    for (int kc = 0; kc < 256; kc += 32) {
      short8 ah = *(const short8*)(arh + kc);
      short8 al = *(const short8*)(arl + kc);
#pragma unroll
      for (int nt = 0; nt < 4; nt++) {
        short8 bh_ = *(const short8*)(Xh + ((size_t)b * NN + nBase + nt * 16 + l15) * 256 + kc + quad * 8);
        short8 bl_ = *(const short8*)(Xl + ((size_t)b * NN + nBase + nt * 16 + l15) * 256 + kc + quad * 8);
        acc[nt] = __builtin_amdgcn_mfma_f32_16x16x32_bf16(ah, bh_, acc[nt], 0, 0, 0);
        acc[nt] = __builtin_amdgcn_mfma_f32_16x16x32_bf16(al, bh_, acc[nt], 0, 0, 0);
        acc[nt] = __builtin_amdgcn_mfma_f32_16x16x32_bf16(ah, bl_, acc[nt], 0, 0, 0);
      }
    }
#pragma unroll
    for (int r = 0; r < 4; r++) {
      int o = oW + quad * 4 + r;
      float bs = bv[o];
      short* yp = Vb + ((size_t)b * 256 + o) * NN + nBase + l15;
#pragma unroll
      for (int nt = 0; nt < 4; nt++) yp[nt * 16] = f2bf_s(acc[nt][r] + bs);
    }
  }
}

// ---------------------------------------------------------------------------
// MFMA attention v7: block-cooperative K/V LDS staging (coalesced, 64-n
// stages, double-buffered, 1 barrier/stage), mt=2 per wave, fixed-swizzle
// P transpose, denominator via ones-MFMA. Grid (18, 64), 256 threads.
// ---------------------------------------------------------------------------
__global__ __launch_bounds__(256) void attn_mfma(const float* __restrict__ q,
                                                 const short* __restrict__ Kb,
                                                 const short* __restrict__ Vb,
                                                 short* __restrict__ O) {
  __shared__ short sK[2][64 * 40];    // row stride 40 shorts (80 B)
  __shared__ short sV[2][32 * 88];    // row stride 88 shorts (176 B)
  __shared__ int sP[4][2][256];       // per-wave P transpose buffers
  const int tid = threadIdx.x;
  const int wave = tid >> 6;
  const int lane = tid & 63;
  const int quad = lane >> 4;
  const int l15 = lane & 15;
  const int bh = blockIdx.y;
  const int b = bh >> 3, head = bh & 7;
  const int mBase = blockIdx.x * 128 + wave * 32;

  // Q B-frags (SCALE folded): B[k=c=quad*8+j][col=m=l15]
  short8 bq[2];
#pragma unroll
  for (int mt = 0; mt < 2; mt++) {
    const float* qp = q + ((size_t)bh * DH + quad * 8) * HW + mBase + mt * 16 + l15;
    short8 v;
#pragma unroll
    for (int j = 0; j < 8; j++) v[j] = f2bf_s(qp[(size_t)j * HW] * SCALE);
    bq[mt] = v;
  }

  // staging thread roles
  const int kn = tid >> 2, kc = (tid & 3) * 8;   // K: 64 n x 64 B
  const int vc = tid >> 3, vn = (tid & 7) * 8;   // V: 32 c x 128 B
  const short* kg = Kb + (size_t)b * NN * 256 + head * DH;  // + n*256 + c
  const short* vg = Vb + ((size_t)b * 256 + head * DH) * NN; // + c*NN + n

  // stage 0
  short8 kreg = *(const short8*)(kg + (size_t)kn * 256 + kc);
  short8 vreg = *(const short8*)(vg + (size_t)vc * NN + vn);
  *(short8*)(&sK[0][kn * 40 + kc]) = kreg;
  *(short8*)(&sV[0][vc * 88 + vn]) = vreg;
  __syncthreads();

  // P swizzle (dwords): phys chunk = logical ^ ((l15>>1)&3)
  const int g = (l15 >> 1) & 3;
  const int row16 = l15 * 16;
  const int wr0 = row16 + (((quad >> 1) ^ g) << 2) + ((quad & 1) << 1);
  const int wr1 = row16 + (((2 + (quad >> 1)) ^ g) << 2) + ((quad & 1) << 1);
  const int rd = row16 + ((quad ^ g) << 2);

  f32x4 oacc[2][2] = {};
  f32x4 dacc[2] = {};
  const short ONE = 0x3F80;
  const short8 ones = {ONE, ONE, ONE, ONE, ONE, ONE, ONE, ONE};

  for (int s = 0; s < 9; s++) {
    const int buf = s & 1;
    if (s + 1 < 9) {  // prefetch next stage into regs
      kreg = *(const short8*)(kg + (size_t)((s + 1) * 64 + kn) * 256 + kc);
      vreg = *(const short8*)(vg + (size_t)vc * NN + (s + 1) * 64 + vn);
    }
#pragma unroll
    for (int nt = 0; nt < 2; nt++) {
      short8 ka0 = *(const short8*)(&sK[buf][(nt * 32 + l15) * 40 + quad * 8]);
      short8 ka1 = *(const short8*)(&sK[buf][(nt * 32 + 16 + l15) * 40 + quad * 8]);
      short8 va0 = *(const short8*)(&sV[buf][l15 * 88 + nt * 32 + quad * 8]);
      short8 va1 = *(const short8*)(&sV[buf][(16 + l15) * 88 + nt * 32 + quad * 8]);
      f32x4 z = {0.f, 0.f, 0.f, 0.f};
      f32x4 st[2][2];
      st[0][0] = __builtin_amdgcn_mfma_f32_16x16x32_bf16(ka0, bq[0], z, 0, 0, 0);
      st[0][1] = __builtin_amdgcn_mfma_f32_16x16x32_bf16(ka1, bq[0], z, 0, 0, 0);
      st[1][0] = __builtin_amdgcn_mfma_f32_16x16x32_bf16(ka0, bq[1], z, 0, 0, 0);
      st[1][1] = __builtin_amdgcn_mfma_f32_16x16x32_bf16(ka1, bq[1], z, 0, 0, 0);
#pragma unroll
      for (int mt = 0; mt < 2; mt++) {
        float p0 = __expf(st[mt][0][0]), p1 = __expf(st[mt][0][1]);
        float p2 = __expf(st[mt][0][2]), p3 = __expf(st[mt][0][3]);
        float p4 = __expf(st[mt][1][0]), p5 = __expf(st[mt][1][1]);
        float p6 = __expf(st[mt][1][2]), p7 = __expf(st[mt][1][3]);
        int* base = &sP[wave][mt][0];
        *(int2*)(base + wr0) = make_int2((int)pkrnd(p0, p1), (int)pkrnd(p2, p3));
        *(int2*)(base + wr1) = make_int2((int)pkrnd(p4, p5), (int)pkrnd(p6, p7));
      }
#pragma unroll
      for (int mt = 0; mt < 2; mt++) {
        short8 pa = *(short8*)(&sP[wave][mt][0] + rd);
        oacc[mt][0] = __builtin_amdgcn_mfma_f32_16x16x32_bf16(pa, va0, oacc[mt][0], 0, 0, 0);
        oacc[mt][1] = __builtin_amdgcn_mfma_f32_16x16x32_bf16(pa, va1, oacc[mt][1], 0, 0, 0);
        dacc[mt] = __builtin_amdgcn_mfma_f32_16x16x32_bf16(pa, ones, dacc[mt], 0, 0, 0);
      }
    }
    if (s + 1 < 9) {
      *(short8*)(&sK[buf ^ 1][kn * 40 + kc]) = kreg;
      *(short8*)(&sV[buf ^ 1][vc * 88 + vn]) = vreg;
    }
    __syncthreads();
  }

#pragma unroll
  for (int mt = 0; mt < 2; mt++) {
    short* ob = O + ((size_t)b * HW + mBase + mt * 16) * 256 + head * DH + l15;
#pragma unroll
    for (int r = 0; r < 4; r++) {
      float inv = 1.0f / dacc[mt][r];
      ob[(size_t)(quad * 4 + r) * 256] = f2bf_s(oacc[mt][0][r] * inv);
      ob[(size_t)(quad * 4 + r) * 256 + 16] = f2bf_s(oacc[mt][1][r] * inv);
    }
  }
}

// ---------------------------------------------------------------------------
// wo GEMM (4-wave o-split): wave owns o-tile 64, block owns m-tile 64.
// X = attn O bf16 (b, m, 256). Grid (36, 8), 256 threads.
// ---------------------------------------------------------------------------
__global__ __launch_bounds__(256) void wo_gemm_mfma(const short* __restrict__ Whi,
                                                    const short* __restrict__ Wlo,
                                                    const float* __restrict__ bias,
                                                    const short* __restrict__ X,
                                                    float* __restrict__ Y) {
  const int tid = threadIdx.x;
  const int wave = tid >> 6;
  const int lane = tid & 63;
  const int quad = lane >> 4;
  const int l15 = lane & 15;
  const int b = blockIdx.y;
  const int oBase = wave * 64;
  const int mBase = blockIdx.x * 64;

  f32x4 acc[4][4] = {};
  for (int kc = 0; kc < 256; kc += 32) {
    short8 ah[4], al[4];
#pragma unroll
    for (int os = 0; os < 4; os++) {
      ah[os] = *(const short8*)(Whi + (size_t)(oBase + os * 16 + l15) * 256 + kc + quad * 8);
      al[os] = *(const short8*)(Wlo + (size_t)(oBase + os * 16 + l15) * 256 + kc + quad * 8);
    }
#pragma unroll
    for (int mt = 0; mt < 4; mt++) {
      short8 bx = *(const short8*)(X + ((size_t)b * HW + mBase + mt * 16 + l15) * 256 + kc + quad * 8);
#pragma unroll
      for (int os = 0; os < 4; os++) {
        acc[os][mt] = __builtin_amdgcn_mfma_f32_16x16x32_bf16(ah[os], bx, acc[os][mt], 0, 0, 0);
        acc[os][mt] = __builtin_amdgcn_mfma_f32_16x16x32_bf16(al[os], bx, acc[os][mt], 0, 0, 0);
      }
    }
  }

#pragma unroll
  for (int os = 0; os < 4; os++)
#pragma unroll
    for (int r = 0; r < 4; r++) {
      int o = oBase + os * 16 + quad * 4 + r;
      float bs = bias[o];
      float* yp = Y + ((size_t)b * 256 + o) * HW + mBase + l15;
#pragma unroll
      for (int mt = 0; mt < 4; mt++) yp[mt * 16] = acc[os][mt][r] + bs;
    }
}

// ---------------------------------------------------------------------------
extern "C" void kernel_launch(void* const* d_in, const int* in_sizes, int n_in,
                              void* d_out, int out_size, void* d_ws, size_t ws_size,
                              hipStream_t stream) {
  const float* x    = (const float*)d_in[0];
  const float* kv   = (const float*)d_in[1];
  const float* wq   = (const float*)d_in[2];
  const float* bq   = (const float*)d_in[3];
  const float* wk   = (const float*)d_in[4];
  const float* bk   = (const float*)d_in[5];
  const float* wv   = (const float*)d_in[6];
  const float* bv   = (const float*)d_in[7];
  const float* w_dw = (const float*)d_in[8];
  const float* b_dw = (const float*)d_in[9];
  const float* ln_w = (const float*)d_in[10];
  const float* ln_b = (const float*)d_in[11];
  const float* w_off= (const float*)d_in[12];
  const float* wo   = (const float*)d_in[13];
  const float* bo   = (const float*)d_in[14];
  float* out = (float*)d_out;
  float* ws = (float*)d_ws;

  // workspace (float slots), lifetimes:
  //   q     [0,        4718592)  fp32, born gemm_q, dies after attn
  //   Xth/O [4718592,  7077888)  Xth dies after gemm_q; O born in attn
  //   Xtl   [7077888,  9437184)  dies after gemm_q; then:
  //     kvsTh [7077888, 7667712), kvsTl [7667712, 8257536)
  //     Kb    [8257536, 8847360), Vb    [8847360, 9437184)
  //   planes [9437184, 9699328)  8 x 65536 bf16
  float* q     = ws;
  short* Xth   = (short*)(ws + 4718592);
  short* O     = (short*)(ws + 4718592);
  short* Xtl   = (short*)(ws + 7077888);
  short* kvsTh = (short*)(ws + 7077888);
  short* kvsTl = (short*)(ws + 7667712);
  short* Kb    = (short*)(ws + 8257536);
  short* Vb    = (short*)(ws + 8847360);
  short* Wqh   = (short*)(ws + 9437184);
  short* Wql = Wqh + 65536;
  short* Wkh = Wql + 65536;
  short* Wkl = Wkh + 65536;
  short* Wvh = Wkl + 65536;
  short* Wvl = Wvh + 65536;
  short* Woh = Wvl + 65536;
  short* Wol = Woh + 65536;

  prep<<<dim3(1408), dim3(256), 0, stream>>>(x, wq, wk, wv, wo, Xth, Xtl,
                                             Wqh, Wql, Wkh, Wkl, Wvh, Wvl, Woh, Wol);
  gemm_q_mfma<<<dim3(HW / 64, BB), dim3(256), 0, stream>>>(Wqh, Wql, bq, Xth, Xtl, q);
  dw_sample_kernel<<<dim3(BH * NN / 16), dim3(64), 0, stream>>>(
      q, kv, w_dw, b_dw, ln_w, ln_b, w_off, kvsTh, kvsTl);
  kv_gemm_mfma<<<dim3(NN / 64, 8, BB), dim3(256), 0, stream>>>(
      Wkh, Wkl, bk, Wvh, Wvl, bv, kvsTh, kvsTl, Kb, Vb);
  attn_mfma<<<dim3(HW / 128, BH), dim3(256), 0, stream>>>(q, Kb, Vb, O);
  wo_gemm_mfma<<<dim3(HW / 64, BB), dim3(256), 0, stream>>>(Woh, Wol, bo, O, out);
}